// Round 15
// baseline (52.352 us; speedup 1.0000x reference)
//
#include <hip/hip_runtime.h>
#include <math.h>

#define A_TOTAL 250000
#define BCNT 8
#define NANN 16
#define GX 256
#define NTHR 256
#define STRIDE (GX * NTHR)        // 65536
#define IDXM 0x3FFFFu             // 18-bit inverted-anchor field (250000 < 2^18)
#define QMASK 0xFFFC0000u         // top-14-bit truncated-iou field

// ws layout (bytes):
//  [0,    5120) table f32 [8][160]: [0,64) box4 x1,y1,x2,y2 ; [64,80) area ;
//                                   [80,144) gt4 cx,cy,th,len ; [144,160) cls
//  [8192, 270336) part [8][256][32] u32/f32: [0..16) keys, [16..19) sums
// No memset: every consumed word is written by a kernel earlier in the stream.

__device__ __forceinline__ float rfl(float x) {
    return __uint_as_float(__builtin_amdgcn_readfirstlane(__float_as_uint(x)));
}

__device__ __forceinline__ float4 pred_cal(float4 ap, float4 r, float aw, float ah) {
    float cxa = (ap.x + ap.z) * 0.5f, cya = (ap.y + ap.w) * 0.5f;
    float L = sqrtf(aw * aw + ah * ah);
    float th = (ap.x == ap.z) ? copysignf(1.5707963267948966f, ah) : atanf(ah / aw);
    return make_float4(r.x * aw + cxa, r.y * ah + cya, r.z + th, expf(r.w) * L);
}

__device__ __forceinline__ float sl1(float4 pr, float4 g) {
    float s = 0.f, d, ad;
    d = pr.x - g.x; ad = fabsf(d); s += (ad < 1.f) ? 0.5f * d * d : ad - 0.5f;
    d = pr.y - g.y; ad = fabsf(d); s += (ad < 1.f) ? 0.5f * d * d : ad - 0.5f;
    d = pr.z - g.z; ad = fabsf(d); s += (ad < 1.f) ? 0.5f * d * d : ad - 0.5f;
    d = pr.w - g.w; ad = fabsf(d); s += (ad < 1.f) ? 0.5f * d * d : ad - 0.5f;
    return s * 0.25f;
}

__device__ __forceinline__ float focal4m(float4 p4, unsigned mask) {
    float pv[4] = {p4.x, p4.y, p4.z, p4.w};
    float fl = 0.f;
#pragma unroll
    for (int c = 0; c < 4; c++) {
        float pc = fminf(fmaxf(pv[c], 1e-4f), 1.f - 1e-4f);
        fl += ((mask >> c) & 1) ? 0.25f * (1.f - pc) * (1.f - pc) * (-__logf(pc))
                                : 0.75f * pc * pc * (-__logf(1.f - pc));
    }
    return fl;
}

__global__ __launch_bounds__(256) void detloss_init(
    const float* __restrict__ ann, float* __restrict__ table)
{
    int tid = threadIdx.x;
    if (tid < BCNT * NANN) {
        int b = tid >> 4, n = tid & 15;
        const float* a5 = ann + tid * 5;
        float cx = a5[0], cy = a5[1], th = a5[2], ln = a5[3], cl = a5[4];
        bool valid = (cl != -1.0f);
        float dx = fabsf(0.5f * ln * cosf(th));
        float dy = fabsf(0.5f * ln * sinf(th));
        float x1 = cx - dx, y1 = cy - dy, x2 = cx + dx, y2 = cy + dy;
        float ar = (x2 - x1) * (y2 - y1);
        if (!valid) { x1 = y1 = x2 = y2 = 3.0e8f; ar = 1.0e30f; }
        float* tb = table + b * 160;
        tb[4 * n + 0] = x1; tb[4 * n + 1] = y1; tb[4 * n + 2] = x2; tb[4 * n + 3] = y2;
        tb[64 + n] = ar;
        tb[80 + 4 * n + 0] = cx; tb[80 + 4 * n + 1] = cy;
        tb[80 + 4 * n + 2] = th; tb[80 + 4 * n + 3] = ln;
        tb[144 + n] = cl;
    }
}

__global__ __launch_bounds__(NTHR, 4) void detloss_main(
    const float* __restrict__ cls, const float* __restrict__ reg,
    const float* __restrict__ anchors, const float* __restrict__ table,
    unsigned* __restrict__ part)
{
    int b = blockIdx.y;
    int tid = threadIdx.x;
    __shared__ float sGT[NANN][5];
    __shared__ unsigned sKey[4][NANN];
    __shared__ float sPart[4][3];

    const float* tb = table + b * 160;
    if (tid < NANN) {
        sGT[tid][0] = tb[80 + 4 * tid + 0]; sGT[tid][1] = tb[80 + 4 * tid + 1];
        sGT[tid][2] = tb[80 + 4 * tid + 2]; sGT[tid][3] = tb[80 + 4 * tid + 3];
        sGT[tid][4] = tb[144 + tid];
    }

    // ann box constants: uniform table loads -> SGPR (no transcendentals in main)
    float sx1[NANN], sy1[NANN], sx2[NANN], sy2[NANN], bar[NANN];
#pragma unroll
    for (int n = 0; n < NANN; n++) {
        sx1[n] = rfl(tb[4 * n + 0]); sy1[n] = rfl(tb[4 * n + 1]);
        sx2[n] = rfl(tb[4 * n + 2]); sy2[n] = rfl(tb[4 * n + 3]);
        bar[n] = rfl(tb[64 + n]);
    }
    __syncthreads();

    unsigned bmk[NANN];
#pragma unroll
    for (int n = 0; n < NANN; n++) bmk[n] = 0u;
    float clsS = 0.f, regS = 0.f, nposS = 0.f;

    const float4* clsB = (const float4*)(cls + (size_t)b * A_TOTAL * 4);
    const float4* regB = (const float4*)(reg + (size_t)b * A_TOTAL * 4);
    const float4* anc4 = (const float4*)anchors;

    // main loop: single-ahead anchor prefetch; best = pure fmax chain (no barg)
    int a = blockIdx.x * NTHR + tid;
    float4 ap = (a < A_TOTAL) ? anc4[a] : make_float4(0.f, 0.f, 0.f, 0.f);
    while (a < A_TOTAL) {
        float4 p4 = clsB[a];
        int a2 = a + STRIDE;
        int apre = (a2 < A_TOTAL) ? a2 : a;
        float4 apn = anc4[apre];
        unsigned inv_a = IDXM - (unsigned)a;

        float aw = ap.z - ap.x, ah = ap.w - ap.y;
        float aarea = aw * ah;
        float best = 0.f;
#pragma unroll
        for (int n = 0; n < NANN; n++) {
            float iw = fminf(ap.z, sx2[n]) - fmaxf(ap.x, sx1[n]);
            float ih = fminf(ap.w, sy2[n]) - fmaxf(ap.y, sy1[n]);
            iw = fmaxf(iw, 0.f); ih = fmaxf(ih, 0.f);
            float inter = iw * ih;
            float ua = fmaxf(aarea + bar[n] - inter, 1e-8f);
            float iou = inter * __builtin_amdgcn_rcpf(ua);
            best = fmaxf(best, iou);
            unsigned kc = (__float_as_uint(iou) & QMASK) | inv_a;
            bmk[n] = (kc > bmk[n]) ? kc : bmk[n];
        }
        if (best < 0.4f || best >= 0.5f) {
            bool pos = (best >= 0.5f);
            float pc0 = fminf(fmaxf(p4.x, 1e-4f), 1.f - 1e-4f);
            float pc1 = fminf(fmaxf(p4.y, 1e-4f), 1.f - 1e-4f);
            float pc2 = fminf(fmaxf(p4.z, 1e-4f), 1.f - 1e-4f);
            float pc3 = fminf(fmaxf(p4.w, 1e-4f), 1.f - 1e-4f);
            float fl = 0.75f * pc0 * pc0 * (-__logf(1.f - pc0))
                     + 0.75f * pc1 * pc1 * (-__logf(1.f - pc1))
                     + 0.75f * pc2 * pc2 * (-__logf(1.f - pc2))
                     + 0.75f * pc3 * pc3 * (-__logf(1.f - pc3));
            if (pos) {
                // rare: recover argmax via reverse-order UNROLLED replay (proven exact)
                int barg = 0;
#pragma unroll
                for (int n = NANN - 1; n >= 0; n--) {
                    float iw = fminf(ap.z, sx2[n]) - fmaxf(ap.x, sx1[n]);
                    float ih = fminf(ap.w, sy2[n]) - fmaxf(ap.y, sy1[n]);
                    iw = fmaxf(iw, 0.f); ih = fmaxf(ih, 0.f);
                    float inter = iw * ih;
                    float ua = fmaxf(aarea + bar[n] - inter, 1e-8f);
                    float iou = inter * __builtin_amdgcn_rcpf(ua);
                    if (iou == best) barg = n;
                }
                int ac = (int)sGT[barg][4];
                float pc = ac == 0 ? pc0 : ac == 1 ? pc1 : ac == 2 ? pc2 : pc3;
                fl += 0.25f * (1.f - pc) * (1.f - pc) * (-__logf(pc))
                    - 0.75f * pc * pc * (-__logf(1.f - pc));
                nposS += 1.f;
                float4 r = regB[a];
                float4 pr = pred_cal(ap, r, aw, ah);
                float4 g = make_float4(sGT[barg][0], sGT[barg][1], sGT[barg][2], sGT[barg][3]);
                regS += sl1(pr, g);
            }
            clsS += fl;
        }
        ap = apn; a = a2;
    }

    // block-private partials: NO global atomics
    int lane = tid & 63, wv = tid >> 6;
#pragma unroll
    for (int n = 0; n < NANN; n++) {
        unsigned k = bmk[n];
#pragma unroll
        for (int off = 1; off < 64; off <<= 1) {
            unsigned o = __shfl_xor(k, off, 64);
            k = (o > k) ? o : k;
        }
        if (lane == 0) sKey[wv][n] = k;
    }
#pragma unroll
    for (int off = 1; off < 64; off <<= 1) {
        clsS  += __shfl_xor(clsS, off, 64);
        regS  += __shfl_xor(regS, off, 64);
        nposS += __shfl_xor(nposS, off, 64);
    }
    if (lane == 0) { sPart[wv][0] = clsS; sPart[wv][1] = regS; sPart[wv][2] = nposS; }
    __syncthreads();

    unsigned* pb = part + ((size_t)(b * GX + blockIdx.x)) * 32;
    if (tid < NANN) {
        unsigned m = sKey[0][tid];
#pragma unroll
        for (int w = 1; w < 4; w++) m = (sKey[w][tid] > m) ? sKey[w][tid] : m;
        pb[tid] = m;
    }
    if (tid == 0) {
        float c0 = 0, c1 = 0, c2 = 0;
        for (int w = 0; w < 4; w++) { c0 += sPart[w][0]; c1 += sPart[w][1]; c2 += sPart[w][2]; }
        ((float*)pb)[16] = c0;
        ((float*)pb)[17] = c1;
        ((float*)pb)[18] = c2;
    }
}

__global__ __launch_bounds__(256) void detloss_reduce(
    const float* __restrict__ cls, const float* __restrict__ reg,
    const float* __restrict__ anchors, const float* __restrict__ table,
    const unsigned* __restrict__ part, float* __restrict__ out)
{
    int tid = threadIdx.x;
    __shared__ unsigned rKey[BCNT][NANN];
    __shared__ float rAcc[BCNT][3];
    __shared__ int fForce[BCNT * NANN];
    __shared__ float fAcc[BCNT * 3];

    if (tid < BCNT * NANN) {
        int b = tid >> 4, n = tid & 15;
        unsigned m = 0u;
        for (int k = 0; k < GX; k++) {
            unsigned v = part[((size_t)(b * GX + k)) * 32 + n];
            m = (v > m) ? v : m;
        }
        rKey[b][n] = m;
    } else if (tid < BCNT * NANN + BCNT * 3) {
        int t = tid - BCNT * NANN; int b = t / 3, j = t % 3;
        float s = 0.f;
        for (int k = 0; k < GX; k++)
            s += ((const float*)part)[((size_t)(b * GX + k)) * 32 + 16 + j];
        rAcc[b][j] = s;
    }
    if (tid < BCNT * 3) fAcc[tid] = 0.f;
    __syncthreads();

    if (tid < BCNT * NANN) {
        int b = tid >> 4, n = tid & 15;
        unsigned k = rKey[b][n];
        float amax = __uint_as_float(k & QMASK);
        float cl = table[b * 160 + 144 + n];
        bool force = (cl != -1.f) && (amax < 0.5f);
        int anchor = (int)(IDXM - (k & IDXM));
        fForce[tid] = (force && anchor >= 0 && anchor < A_TOTAL) ? anchor : -1;
    }
    __syncthreads();

    if (tid < BCNT * NANN) {
        int fb = tid >> 4, fn = tid & 15;
        const float* tbf = table + fb * 160;
        int idx = fForce[tid];
        bool first = (idx >= 0);
        for (int m = 0; m < fn; m++) if (fForce[fb * NANN + m] == idx) first = false;
        if (idx >= 0 && first) {
            const float4* clsBf = (const float4*)(cls + (size_t)fb * A_TOTAL * 4);
            const float4* regBf = (const float4*)(reg + (size_t)fb * A_TOTAL * 4);
            float4 ap2 = ((const float4*)anchors)[idx];
            float aw = ap2.z - ap2.x, ah = ap2.w - ap2.y;
            float aarea = aw * ah;
            // old state: fmax chain + reverse replay, same table values as main
            float best = 0.f;
#pragma unroll
            for (int m = 0; m < NANN; m++) {
                float iw = fminf(ap2.z, tbf[4 * m + 2]) - fmaxf(ap2.x, tbf[4 * m + 0]);
                float ih = fminf(ap2.w, tbf[4 * m + 3]) - fmaxf(ap2.y, tbf[4 * m + 1]);
                iw = fmaxf(iw, 0.f); ih = fmaxf(ih, 0.f);
                float inter = iw * ih;
                float ua = fmaxf(aarea + tbf[64 + m] - inter, 1e-8f);
                float iou = inter * __builtin_amdgcn_rcpf(ua);
                best = fmaxf(best, iou);
            }
            int barg = 0;
#pragma unroll
            for (int m = NANN - 1; m >= 0; m--) {
                float iw = fminf(ap2.z, tbf[4 * m + 2]) - fmaxf(ap2.x, tbf[4 * m + 0]);
                float ih = fminf(ap2.w, tbf[4 * m + 3]) - fmaxf(ap2.y, tbf[4 * m + 1]);
                iw = fmaxf(iw, 0.f); ih = fmaxf(ih, 0.f);
                float inter = iw * ih;
                float ua = fmaxf(aarea + tbf[64 + m] - inter, 1e-8f);
                float iou = inter * __builtin_amdgcn_rcpf(ua);
                if (iou == best) barg = m;
            }
            float4 p4 = clsBf[idx];
            float oldc = 0.f, oldr = 0.f, oldn = 0.f;
            if (best < 0.4f || best >= 0.5f) {
                bool pos = (best >= 0.5f);
                unsigned msk = pos ? (1u << (int)tbf[144 + barg]) : 0u;
                oldc = focal4m(p4, msk);
                if (pos) {
                    oldn = 1.f;
                    float4 r = regBf[idx];
                    float4 pr = pred_cal(ap2, r, aw, ah);
                    float4 g = make_float4(tbf[80 + 4 * barg + 0], tbf[80 + 4 * barg + 1],
                                           tbf[80 + 4 * barg + 2], tbf[80 + 4 * barg + 3]);
                    oldr = sl1(pr, g);
                }
            }
            unsigned cmask = 0; int lastm = fn;
            for (int m = 0; m < NANN; m++)
                if (fForce[fb * NANN + m] == idx) { cmask |= 1u << (int)tbf[144 + m]; lastm = m; }
            float newc = focal4m(p4, cmask);
            float4 r = regBf[idx];
            float4 pr = pred_cal(ap2, r, aw, ah);
            float4 g = make_float4(tbf[80 + 4 * lastm + 0], tbf[80 + 4 * lastm + 1],
                                   tbf[80 + 4 * lastm + 2], tbf[80 + 4 * lastm + 3]);
            float newr = sl1(pr, g);
            atomicAdd(&fAcc[fb * 3 + 0], newc - oldc);
            atomicAdd(&fAcc[fb * 3 + 1], newr - oldr);
            atomicAdd(&fAcc[fb * 3 + 2], 1.f - oldn);
        }
    }
    __syncthreads();
    if (tid == 0) {
        float cm = 0.f, rm = 0.f;
        for (int b = 0; b < BCNT; b++) {
            float np = fmaxf(rAcc[b][2] + fAcc[b * 3 + 2], 1.f);
            cm += (rAcc[b][0] + fAcc[b * 3 + 0]) / np;
            rm += (rAcc[b][1] + fAcc[b * 3 + 1]) / np;
        }
        out[0] = cm * 0.125f;
        out[1] = rm * 0.125f;
    }
}

extern "C" void kernel_launch(void* const* d_in, const int* in_sizes, int n_in,
                              void* d_out, int out_size, void* d_ws, size_t ws_size,
                              hipStream_t stream) {
    const float* classifications = (const float*)d_in[0];
    const float* regressions     = (const float*)d_in[1];
    const float* anchors_pos     = (const float*)d_in[2];
    const float* annotations     = (const float*)d_in[3];
    float* out = (float*)d_out;

    char* ws = (char*)d_ws;
    float* table = (float*)(ws + 0);             // 5120 B
    unsigned* part = (unsigned*)(ws + 8192);     // 8*256*32*4 = 262144 B

    detloss_init<<<1, 256, 0, stream>>>(annotations, table);
    detloss_main<<<dim3(GX, BCNT), NTHR, 0, stream>>>(
        classifications, regressions, anchors_pos, table, part);
    detloss_reduce<<<1, 256, 0, stream>>>(
        classifications, regressions, anchors_pos, table, part, out);
}

// Round 16
// 49.918 us; speedup vs baseline: 1.0487x; 1.0487x over previous
//
#include <hip/hip_runtime.h>
#include <math.h>

#define A_TOTAL 250000
#define BCNT 8
#define NANN 16
#define GX 128
#define NTHR 256
#define STRIDE (GX * NTHR)        // 32768
#define IDXM 0x3FFFFu             // 18-bit inverted-anchor field (250000 < 2^18); == ~QMASK
#define QMASK 0xFFFC0000u         // top-14-bit truncated-iou field

// ws layout (bytes):
//  [0,    5120) table f32 [8][160]: [0,64) box4 x1,y1,x2,y2 ; [64,80) area ;
//                                   [80,144) gt4 cx,cy,th,len ; [144,160) cls
//  [8192, 139264) part [8][128][32] u32/f32: [0..16) keys, [16..19) sums
// No memset: every consumed word is written by a kernel earlier in the stream.

__device__ __forceinline__ float rfl(float x) {
    return __uint_as_float(__builtin_amdgcn_readfirstlane(__float_as_uint(x)));
}

__device__ __forceinline__ float4 pred_cal(float4 ap, float4 r, float aw, float ah) {
    float cxa = (ap.x + ap.z) * 0.5f, cya = (ap.y + ap.w) * 0.5f;
    float L = sqrtf(aw * aw + ah * ah);
    float th = (ap.x == ap.z) ? copysignf(1.5707963267948966f, ah) : atanf(ah / aw);
    return make_float4(r.x * aw + cxa, r.y * ah + cya, r.z + th, expf(r.w) * L);
}

__device__ __forceinline__ float sl1(float4 pr, float4 g) {
    float s = 0.f, d, ad;
    d = pr.x - g.x; ad = fabsf(d); s += (ad < 1.f) ? 0.5f * d * d : ad - 0.5f;
    d = pr.y - g.y; ad = fabsf(d); s += (ad < 1.f) ? 0.5f * d * d : ad - 0.5f;
    d = pr.z - g.z; ad = fabsf(d); s += (ad < 1.f) ? 0.5f * d * d : ad - 0.5f;
    d = pr.w - g.w; ad = fabsf(d); s += (ad < 1.f) ? 0.5f * d * d : ad - 0.5f;
    return s * 0.25f;
}

__device__ __forceinline__ float focal4m(float4 p4, unsigned mask) {
    float pv[4] = {p4.x, p4.y, p4.z, p4.w};
    float fl = 0.f;
#pragma unroll
    for (int c = 0; c < 4; c++) {
        float pc = fminf(fmaxf(pv[c], 1e-4f), 1.f - 1e-4f);
        fl += ((mask >> c) & 1) ? 0.25f * (1.f - pc) * (1.f - pc) * (-__logf(pc))
                                : 0.75f * pc * pc * (-__logf(1.f - pc));
    }
    return fl;
}

__global__ __launch_bounds__(256) void detloss_init(
    const float* __restrict__ ann, float* __restrict__ table)
{
    int tid = threadIdx.x;
    if (tid < BCNT * NANN) {
        int b = tid >> 4, n = tid & 15;
        const float* a5 = ann + tid * 5;
        float cx = a5[0], cy = a5[1], th = a5[2], ln = a5[3], cl = a5[4];
        bool valid = (cl != -1.0f);
        float dx = fabsf(0.5f * ln * cosf(th));
        float dy = fabsf(0.5f * ln * sinf(th));
        float x1 = cx - dx, y1 = cy - dy, x2 = cx + dx, y2 = cy + dy;
        float ar = (x2 - x1) * (y2 - y1);
        if (!valid) { x1 = y1 = x2 = y2 = 3.0e8f; ar = 1.0e30f; }
        float* tb = table + b * 160;
        tb[4 * n + 0] = x1; tb[4 * n + 1] = y1; tb[4 * n + 2] = x2; tb[4 * n + 3] = y2;
        tb[64 + n] = ar;
        tb[80 + 4 * n + 0] = cx; tb[80 + 4 * n + 1] = cy;
        tb[80 + 4 * n + 2] = th; tb[80 + 4 * n + 3] = ln;
        tb[144 + n] = cl;
    }
}

__global__ __launch_bounds__(NTHR, 4) void detloss_main(
    const float* __restrict__ cls, const float* __restrict__ reg,
    const float* __restrict__ anchors, const float* __restrict__ table,
    unsigned* __restrict__ part)
{
    int b = blockIdx.y;
    int tid = threadIdx.x;
    __shared__ float sGT[NANN][5];
    __shared__ unsigned sKey[4][NANN];
    __shared__ float sPart[4][3];

    const float* tb = table + b * 160;
    if (tid < NANN) {
        sGT[tid][0] = tb[80 + 4 * tid + 0]; sGT[tid][1] = tb[80 + 4 * tid + 1];
        sGT[tid][2] = tb[80 + 4 * tid + 2]; sGT[tid][3] = tb[80 + 4 * tid + 3];
        sGT[tid][4] = tb[144 + tid];
    }

    // ann box constants: uniform table loads -> SGPR (no transcendentals in main)
    float sx1[NANN], sy1[NANN], sx2[NANN], sy2[NANN], bar[NANN];
#pragma unroll
    for (int n = 0; n < NANN; n++) {
        sx1[n] = rfl(tb[4 * n + 0]); sy1[n] = rfl(tb[4 * n + 1]);
        sx2[n] = rfl(tb[4 * n + 2]); sy2[n] = rfl(tb[4 * n + 3]);
        bar[n] = rfl(tb[64 + n]);
    }
    __syncthreads();

    unsigned bmk[NANN];
#pragma unroll
    for (int n = 0; n < NANN; n++) bmk[n] = 0u;
    float clsS = 0.f, regS = 0.f, nposS = 0.f;

    const float4* clsB = (const float4*)(cls + (size_t)b * A_TOTAL * 4);
    const float4* regB = (const float4*)(reg + (size_t)b * A_TOTAL * 4);
    const float4* anc4 = (const float4*)anchors;

    // main loop: single-ahead anchor prefetch; best = pure fmax chain (no barg)
    int a = blockIdx.x * NTHR + tid;
    float4 ap = anc4[a];
    while (a < A_TOTAL) {
        float4 p4 = clsB[a];
        int a2 = a + STRIDE;
        int apre = (a2 < A_TOTAL) ? a2 : a;
        float4 apn = anc4[apre];
        unsigned inv_a = IDXM - (unsigned)a;

        float aw = ap.z - ap.x, ah = ap.w - ap.y;
        float aarea = aw * ah;
        float best = 0.f;
#pragma unroll
        for (int n = 0; n < NANN; n++) {
            float iw = fminf(ap.z, sx2[n]) - fmaxf(ap.x, sx1[n]);
            float ih = fminf(ap.w, sy2[n]) - fmaxf(ap.y, sy1[n]);
            iw = fmaxf(iw, 0.f); ih = fmaxf(ih, 0.f);
            float inter = iw * ih;
            float ua = fmaxf(aarea + bar[n] - inter, 1e-8f);
            float iou = inter * __builtin_amdgcn_rcpf(ua);
            best = fmaxf(best, iou);
            // (a&M)|(b&~M) pattern -> single v_bfi_b32 (IDXM == ~QMASK; inv_a&IDXM == inv_a)
            unsigned kc = (__float_as_uint(iou) & QMASK) | (inv_a & IDXM);
            bmk[n] = (kc > bmk[n]) ? kc : bmk[n];
        }
        if (best < 0.4f || best >= 0.5f) {
            bool pos = (best >= 0.5f);
            float pc0 = fminf(fmaxf(p4.x, 1e-4f), 1.f - 1e-4f);
            float pc1 = fminf(fmaxf(p4.y, 1e-4f), 1.f - 1e-4f);
            float pc2 = fminf(fmaxf(p4.z, 1e-4f), 1.f - 1e-4f);
            float pc3 = fminf(fmaxf(p4.w, 1e-4f), 1.f - 1e-4f);
            float fl = 0.75f * pc0 * pc0 * (-__logf(1.f - pc0))
                     + 0.75f * pc1 * pc1 * (-__logf(1.f - pc1))
                     + 0.75f * pc2 * pc2 * (-__logf(1.f - pc2))
                     + 0.75f * pc3 * pc3 * (-__logf(1.f - pc3));
            if (pos) {
                // rare: recover argmax via reverse-order UNROLLED replay (proven exact)
                int barg = 0;
#pragma unroll
                for (int n = NANN - 1; n >= 0; n--) {
                    float iw = fminf(ap.z, sx2[n]) - fmaxf(ap.x, sx1[n]);
                    float ih = fminf(ap.w, sy2[n]) - fmaxf(ap.y, sy1[n]);
                    iw = fmaxf(iw, 0.f); ih = fmaxf(ih, 0.f);
                    float inter = iw * ih;
                    float ua = fmaxf(aarea + bar[n] - inter, 1e-8f);
                    float iou = inter * __builtin_amdgcn_rcpf(ua);
                    if (iou == best) barg = n;
                }
                int ac = (int)sGT[barg][4];
                float pc = ac == 0 ? pc0 : ac == 1 ? pc1 : ac == 2 ? pc2 : pc3;
                fl += 0.25f * (1.f - pc) * (1.f - pc) * (-__logf(pc))
                    - 0.75f * pc * pc * (-__logf(1.f - pc));
                nposS += 1.f;
                float4 r = regB[a];
                float4 pr = pred_cal(ap, r, aw, ah);
                float4 g = make_float4(sGT[barg][0], sGT[barg][1], sGT[barg][2], sGT[barg][3]);
                regS += sl1(pr, g);
            }
            clsS += fl;
        }
        ap = apn; a = a2;
    }

    // block-private partials: NO global atomics
    int lane = tid & 63, wv = tid >> 6;
#pragma unroll
    for (int n = 0; n < NANN; n++) {
        unsigned k = bmk[n];
#pragma unroll
        for (int off = 1; off < 64; off <<= 1) {
            unsigned o = __shfl_xor(k, off, 64);
            k = (o > k) ? o : k;
        }
        if (lane == 0) sKey[wv][n] = k;
    }
#pragma unroll
    for (int off = 1; off < 64; off <<= 1) {
        clsS  += __shfl_xor(clsS, off, 64);
        regS  += __shfl_xor(regS, off, 64);
        nposS += __shfl_xor(nposS, off, 64);
    }
    if (lane == 0) { sPart[wv][0] = clsS; sPart[wv][1] = regS; sPart[wv][2] = nposS; }
    __syncthreads();

    unsigned* pb = part + ((size_t)(b * GX + blockIdx.x)) * 32;
    if (tid < NANN) {
        unsigned m = sKey[0][tid];
#pragma unroll
        for (int w = 1; w < 4; w++) m = (sKey[w][tid] > m) ? sKey[w][tid] : m;
        pb[tid] = m;
    }
    if (tid == 0) {
        float c0 = 0, c1 = 0, c2 = 0;
        for (int w = 0; w < 4; w++) { c0 += sPart[w][0]; c1 += sPart[w][1]; c2 += sPart[w][2]; }
        ((float*)pb)[16] = c0;
        ((float*)pb)[17] = c1;
        ((float*)pb)[18] = c2;
    }
}

__global__ __launch_bounds__(256) void detloss_reduce(
    const float* __restrict__ cls, const float* __restrict__ reg,
    const float* __restrict__ anchors, const float* __restrict__ table,
    const unsigned* __restrict__ part, float* __restrict__ out)
{
    int tid = threadIdx.x;
    __shared__ unsigned rKey[BCNT][NANN];
    __shared__ float rAcc[BCNT][3];
    __shared__ int fForce[BCNT * NANN];
    __shared__ float fAcc[BCNT * 3];

    if (tid < BCNT * NANN) {
        int b = tid >> 4, n = tid & 15;
        unsigned m = 0u;
        for (int k = 0; k < GX; k++) {
            unsigned v = part[((size_t)(b * GX + k)) * 32 + n];
            m = (v > m) ? v : m;
        }
        rKey[b][n] = m;
    } else if (tid < BCNT * NANN + BCNT * 3) {
        int t = tid - BCNT * NANN; int b = t / 3, j = t % 3;
        float s = 0.f;
        for (int k = 0; k < GX; k++)
            s += ((const float*)part)[((size_t)(b * GX + k)) * 32 + 16 + j];
        rAcc[b][j] = s;
    }
    if (tid < BCNT * 3) fAcc[tid] = 0.f;
    __syncthreads();

    if (tid < BCNT * NANN) {
        int b = tid >> 4, n = tid & 15;
        unsigned k = rKey[b][n];
        float amax = __uint_as_float(k & QMASK);
        float cl = table[b * 160 + 144 + n];
        bool force = (cl != -1.f) && (amax < 0.5f);
        int anchor = (int)(IDXM - (k & IDXM));
        fForce[tid] = (force && anchor >= 0 && anchor < A_TOTAL) ? anchor : -1;
    }
    __syncthreads();

    if (tid < BCNT * NANN) {
        int fb = tid >> 4, fn = tid & 15;
        const float* tbf = table + fb * 160;
        int idx = fForce[tid];
        bool first = (idx >= 0);
        for (int m = 0; m < fn; m++) if (fForce[fb * NANN + m] == idx) first = false;
        if (idx >= 0 && first) {
            const float4* clsBf = (const float4*)(cls + (size_t)fb * A_TOTAL * 4);
            const float4* regBf = (const float4*)(reg + (size_t)fb * A_TOTAL * 4);
            float4 ap2 = ((const float4*)anchors)[idx];
            float aw = ap2.z - ap2.x, ah = ap2.w - ap2.y;
            float aarea = aw * ah;
            // old state: fmax chain + reverse replay, same table values as main
            float best = 0.f;
#pragma unroll
            for (int m = 0; m < NANN; m++) {
                float iw = fminf(ap2.z, tbf[4 * m + 2]) - fmaxf(ap2.x, tbf[4 * m + 0]);
                float ih = fminf(ap2.w, tbf[4 * m + 3]) - fmaxf(ap2.y, tbf[4 * m + 1]);
                iw = fmaxf(iw, 0.f); ih = fmaxf(ih, 0.f);
                float inter = iw * ih;
                float ua = fmaxf(aarea + tbf[64 + m] - inter, 1e-8f);
                float iou = inter * __builtin_amdgcn_rcpf(ua);
                best = fmaxf(best, iou);
            }
            int barg = 0;
#pragma unroll
            for (int m = NANN - 1; m >= 0; m--) {
                float iw = fminf(ap2.z, tbf[4 * m + 2]) - fmaxf(ap2.x, tbf[4 * m + 0]);
                float ih = fminf(ap2.w, tbf[4 * m + 3]) - fmaxf(ap2.y, tbf[4 * m + 1]);
                iw = fmaxf(iw, 0.f); ih = fmaxf(ih, 0.f);
                float inter = iw * ih;
                float ua = fmaxf(aarea + tbf[64 + m] - inter, 1e-8f);
                float iou = inter * __builtin_amdgcn_rcpf(ua);
                if (iou == best) barg = m;
            }
            float4 p4 = clsBf[idx];
            float oldc = 0.f, oldr = 0.f, oldn = 0.f;
            if (best < 0.4f || best >= 0.5f) {
                bool pos = (best >= 0.5f);
                unsigned msk = pos ? (1u << (int)tbf[144 + barg]) : 0u;
                oldc = focal4m(p4, msk);
                if (pos) {
                    oldn = 1.f;
                    float4 r = regBf[idx];
                    float4 pr = pred_cal(ap2, r, aw, ah);
                    float4 g = make_float4(tbf[80 + 4 * barg + 0], tbf[80 + 4 * barg + 1],
                                           tbf[80 + 4 * barg + 2], tbf[80 + 4 * barg + 3]);
                    oldr = sl1(pr, g);
                }
            }
            unsigned cmask = 0; int lastm = fn;
            for (int m = 0; m < NANN; m++)
                if (fForce[fb * NANN + m] == idx) { cmask |= 1u << (int)tbf[144 + m]; lastm = m; }
            float newc = focal4m(p4, cmask);
            float4 r = regBf[idx];
            float4 pr = pred_cal(ap2, r, aw, ah);
            float4 g = make_float4(tbf[80 + 4 * lastm + 0], tbf[80 + 4 * lastm + 1],
                                   tbf[80 + 4 * lastm + 2], tbf[80 + 4 * lastm + 3]);
            float newr = sl1(pr, g);
            atomicAdd(&fAcc[fb * 3 + 0], newc - oldc);
            atomicAdd(&fAcc[fb * 3 + 1], newr - oldr);
            atomicAdd(&fAcc[fb * 3 + 2], 1.f - oldn);
        }
    }
    __syncthreads();
    if (tid == 0) {
        float cm = 0.f, rm = 0.f;
        for (int b = 0; b < BCNT; b++) {
            float np = fmaxf(rAcc[b][2] + fAcc[b * 3 + 2], 1.f);
            cm += (rAcc[b][0] + fAcc[b * 3 + 0]) / np;
            rm += (rAcc[b][1] + fAcc[b * 3 + 1]) / np;
        }
        out[0] = cm * 0.125f;
        out[1] = rm * 0.125f;
    }
}

extern "C" void kernel_launch(void* const* d_in, const int* in_sizes, int n_in,
                              void* d_out, int out_size, void* d_ws, size_t ws_size,
                              hipStream_t stream) {
    const float* classifications = (const float*)d_in[0];
    const float* regressions     = (const float*)d_in[1];
    const float* anchors_pos     = (const float*)d_in[2];
    const float* annotations     = (const float*)d_in[3];
    float* out = (float*)d_out;

    char* ws = (char*)d_ws;
    float* table = (float*)(ws + 0);             // 5120 B
    unsigned* part = (unsigned*)(ws + 8192);     // 8*128*32*4 = 131072 B

    detloss_init<<<1, 256, 0, stream>>>(annotations, table);
    detloss_main<<<dim3(GX, BCNT), NTHR, 0, stream>>>(
        classifications, regressions, anchors_pos, table, part);
    detloss_reduce<<<1, 256, 0, stream>>>(
        classifications, regressions, anchors_pos, table, part, out);
}